// Round 6
// baseline (232.608 us; speedup 1.0000x reference)
//
#include <hip/hip_runtime.h>

// NMS3D (4,4,32,256,256) fp32, strict 26-neighbor max.
// R12: ZERO-sync design — no LDS, no barrier, no DMA. Fully independent waves
// with a register-resident rolling window.
// R11 post-mortem: normal stores + XCD swizzle both hurt (70us slice) ->
// reverted; R9 re-confirmed champion (62us slice). Corrected model: FETCH is
// HBM traffic and the 512MB harness fills flush L3 between iterations, so
// 89MB FETCH + 134MB WRITE = 223MB compulsory HBM -> 36-41us floor. R9's
// residual ~21us is the stage->vmcnt(0)drain->barrier convergence, serial per
// block; block-level TLP scan (2/4/6 blk/CU = 65/62/64us) proved more blocks
// can't hide it.
// R12: wave owns (bc, d, 16 h-rows); 4-row x 3-plane v4f window in registers
// (48 VGPR); step i: issue 3 loads of row i+3 (distance-1 prefetch, adjacent
// so one waitcnt covers all), compute output i from rows i..i+2, nt-store.
// All slot indices compile-time (full unroll, rule #20). Wave-uniform load
// base -> saddr+voffset form. 2048 blocks; ~70-80 VGPR -> 16 waves/CU.
// Math verified absmax 0.0 in R6-R11: separable vertical max + lane shuffles.

typedef float v4f __attribute__((ext_vector_type(4)));

constexpr int W  = 256;
constexpr int H  = 256;
constexpr int D  = 32;
constexpr int SH = W;
constexpr int SD = W * H;
constexpr int KD  = 4;                 // planes per block (1 per wave)
constexpr int HCW = 16;                // h rows per wave
constexpr int BC = 16;                 // B*CH
constexpr int DG = D / KD;             // 8
constexpr int HG = H / HCW;            // 16
constexpr int NWG = BC * DG * HG;      // 2048 blocks

__device__ __forceinline__ v4f vmax4(v4f a, v4f b) {
    return (v4f){fmaxf(a.x, b.x), fmaxf(a.y, b.y), fmaxf(a.z, b.z), fmaxf(a.w, b.w)};
}

__global__ __launch_bounds__(256, 4) void nms3d_kernel(const float* __restrict__ x,
                                                       float* __restrict__ out) {
    const int blk  = blockIdx.x;
    const int wv   = threadIdx.x >> 6;   // 0..3
    const int lane = threadIdx.x & 63;
    const int hg   = blk & (HG - 1);            // fastest: h-neighbors share planes in L2
    const int dg   = (blk >> 4) & (DG - 1);
    const int bc   = blk >> 7;
    const int d    = dg * KD + wv;              // this wave's output plane
    const int h0   = hg * HCW;

    const float* vol = x + bc * (D * SD);       // wave-uniform base (saddr form)
    const int pm = d == 0     ? 0     : d - 1;
    const int pp = d == D - 1 ? D - 1 : d + 1;
    // 32-bit per-plane offsets (8 MB volume): saddr = vol, voffset = om + row
    const int om = pm * SD + (lane << 2);
    const int o0 = d  * SD + (lane << 2);
    const int op = pp * SD + (lane << 2);

    const bool dv = (d > 0) && (d < D - 1);
    float* ovol = out + bc * (D * SD) + d * SD + (lane << 2);

    // 4-slot rolling window: rows i..i+3 live in slots (i..i+3)&3.
    v4f rm[4], r0[4], rp[4];

    // prologue: local rows 0,1,2 (global h0-1 .. h0+1; only low clamp possible)
    #pragma unroll
    for (int r = 0; r < 3; ++r) {
        int hh = h0 - 1 + r; hh = hh < 0 ? 0 : hh;
        const int o = hh * SH;
        rm[r] = *(const v4f*)(vol + om + o);
        r0[r] = *(const v4f*)(vol + o0 + o);
        rp[r] = *(const v4f*)(vol + op + o);
    }

    #pragma unroll
    for (int i = 0; i < HCW; ++i) {
        // distance-1 prefetch: local row i+3 (needed first by output i+1).
        // Last useful local row is HCW+1 -> compile-time skip on final iter.
        if (i + 3 <= HCW + 1) {
            int hh = h0 - 1 + (i + 3); hh = hh > H - 1 ? H - 1 : hh;  // >=2, low ok
            const int o = hh * SH, s = (i + 3) & 3;
            rm[s] = *(const v4f*)(vol + om + o);
            r0[s] = *(const v4f*)(vol + o0 + o);
            rp[s] = *(const v4f*)(vol + op + o);
        }
        const int s0 = i & 3, s1 = (i + 1) & 3, s2 = (i + 2) & 3;

        // separable: per-plane maxes over the 3 h-rows (verified math)
        const v4f a3m = vmax4(vmax4(rm[s0], rm[s1]), rm[s2]);   // plane d-1
        const v4f a3p = vmax4(vmax4(rp[s0], rp[s1]), rp[s2]);   // plane d+1
        const v4f a20 = vmax4(r0[s0], r0[s2]);                  // plane d, h +- 1
        const v4f v8  = vmax4(vmax4(a3m, a3p), a20);            // 8 non-center rows
        const v4f c   = r0[s1];

        const float l8 = __shfl_up(v8.w, 1);     // lane0 garbage, masked
        const float r8 = __shfl_down(v8.x, 1);   // lane63 garbage, masked
        const float lc = __shfl_up(c.w, 1);
        const float rc = __shfl_down(c.x, 1);

        float n0 = fmaxf(fmaxf(l8,   v8.x), v8.y);
        float n1 = fmaxf(fmaxf(v8.x, v8.y), v8.z);
        float n2 = fmaxf(fmaxf(v8.y, v8.z), v8.w);
        float n3 = fmaxf(fmaxf(v8.z, v8.w), r8);
        n0 = fmaxf(n0, fmaxf(lc,  c.y));
        n1 = fmaxf(n1, fmaxf(c.x, c.z));
        n2 = fmaxf(n2, fmaxf(c.y, c.w));
        n3 = fmaxf(n3, fmaxf(c.z, rc));

        const int h = h0 + i;
        const bool hv = (h > 0) && (h < H - 1);   // wave-uniform
        const bool v  = hv && dv;
        v4f o;
        o.x = (v && lane > 0  && c.x > n0) ? c.x : 0.f;
        o.y = (v && c.y > n1) ? c.y : 0.f;
        o.z = (v && c.z > n2) ? c.z : 0.f;
        o.w = (v && lane < 63 && c.w > n3) ? c.w : 0.f;
        __builtin_nontemporal_store(o, (v4f*)(ovol + h * SH));   // nt: champion cfg
    }
}

extern "C" void kernel_launch(void* const* d_in, const int* in_sizes, int n_in,
                              void* d_out, int out_size, void* d_ws, size_t ws_size,
                              hipStream_t stream) {
    const float* x = (const float*)d_in[0];
    float* out = (float*)d_out;
    // blocks = BC * DG * HG = 16*8*16 = 2048, 256 threads each
    nms3d_kernel<<<NWG, 256, 0, stream>>>(x, out);
}

// Round 7
// 231.730 us; speedup vs baseline: 1.0038x; 1.0038x over previous
//
#include <hip/hip_runtime.h>

// NMS3D (4,4,32,256,256) fp32, strict 26-neighbor max.
// R13: wave-private LDS DMA rings — ZERO barriers + counted vmcnt + DMA.
// Synthesis of the session's two proven halves:
//   - R12 post-mortem: plain-load register pipelines ALWAYS de-pipeline
//     (VGPR=40 proved the window was never resident; vmcnt(0)/iter, 375cy
//     serialized). Only global_load_lds DMA survives hipcc (no SSA consumer
//     to sink).
//   - R8 proved counted s_waitcnt vmcnt(N) over DMA works mechanically; its
//     cost was BLOCK-wide lockstep barriers (waves converging 2x/step).
// R13: each wave owns (bc, d, 16 h-rows) + a PRIVATE 12 KiB LDS ring
// (4 entries x 3 planes x 1 KiB row). No cross-wave sharing -> no barrier
// ever. Per step i: issue 3 DMAs for entry i+3 (distance-2 prefetch),
// s_waitcnt vmcnt(4) (retires entry i+2: newest-4 = [store(i-1), new 3 DMA]),
// ds_read_b128 entry i+2 into a static-indexed register window, compute
// (verified separable max + shuffles, absmax 0.0 R6-R12), nt-store.
// 48 KiB/block -> 3 blocks/CU (12 waves), 2048 blocks = 8/CU turnover.
// rule-#18 guards: sched_barrier(0) + "memory"-clobber asm around waits.

typedef float v4f __attribute__((ext_vector_type(4)));

constexpr int W  = 256;
constexpr int H  = 256;
constexpr int D  = 32;
constexpr int SH = W;
constexpr int SD = W * H;
constexpr int KD  = 4;                 // planes per block (1 per wave)
constexpr int HCW = 16;                // output h rows per wave
constexpr int BC  = 16;                // B*CH
constexpr int DG  = D / KD;            // 8
constexpr int HG  = H / HCW;           // 16
constexpr int NWG = BC * DG * HG;      // 2048 blocks
constexpr int EF  = 3 * W;             // floats per ring entry (3 planes x 1 row)
constexpr int RF  = 4 * EF;            // floats per wave ring (4 entries) = 3072

__device__ __forceinline__ v4f vmax4(v4f a, v4f b) {
    return (v4f){fmaxf(a.x, b.x), fmaxf(a.y, b.y), fmaxf(a.z, b.z), fmaxf(a.w, b.w)};
}

// Stage entry j (global row h0-1+j, clamped) of all 3 planes into ring slot
// j&3. Ring base is wave-uniform (DMA constraint); lane i's 16B land at
// rowbase + 16*i -> exact row-major row. om/o0/op carry the per-lane offset.
__device__ __forceinline__ void stage_entry(const float* __restrict__ vol,
                                            float* ring, int j, int h0,
                                            int om, int o0, int op) {
    int hh = h0 - 1 + j; hh = hh < 0 ? 0 : (hh > H - 1 ? H - 1 : hh);
    const int ro = hh * SH;
    float* dst = ring + (j & 3) * EF;
    __builtin_amdgcn_global_load_lds(
        (const __attribute__((address_space(1))) unsigned int*)(vol + om + ro),
        (__attribute__((address_space(3))) unsigned int*)(dst + 0 * W), 16, 0, 0);
    __builtin_amdgcn_global_load_lds(
        (const __attribute__((address_space(1))) unsigned int*)(vol + o0 + ro),
        (__attribute__((address_space(3))) unsigned int*)(dst + 1 * W), 16, 0, 0);
    __builtin_amdgcn_global_load_lds(
        (const __attribute__((address_space(1))) unsigned int*)(vol + op + ro),
        (__attribute__((address_space(3))) unsigned int*)(dst + 2 * W), 16, 0, 0);
}

__global__ __launch_bounds__(256, 3) void nms3d_kernel(const float* __restrict__ x,
                                                       float* __restrict__ out) {
    __shared__ float lds[4 * RF];      // 48 KiB: 12 KiB private ring per wave

    const int blk  = blockIdx.x;
    const int wv   = threadIdx.x >> 6;   // 0..3
    const int lane = threadIdx.x & 63;
    const int hg   = blk & (HG - 1);            // fastest: h-neighbor strips adjacent
    const int dg   = (blk >> 4) & (DG - 1);
    const int bc   = blk >> 7;
    const int d    = dg * KD + wv;              // this wave's output plane
    const int h0   = hg * HCW;

    const float* vol = x + bc * (D * SD);       // wave-uniform base
    const int pm = d == 0     ? 0     : d - 1;  // clamped neighbor planes
    const int pp = d == D - 1 ? D - 1 : d + 1;
    const int om = pm * SD + (lane << 2);       // per-lane 32-bit offsets (8MB vol)
    const int o0 = d  * SD + (lane << 2);
    const int op = pp * SD + (lane << 2);

    const bool dv = (d > 0) && (d < D - 1);
    float* ovol = out + bc * (D * SD) + d * SD + (lane << 2);
    float* ring = lds + wv * RF;
    const float* cring = ring + (lane << 2);    // read side: per-lane 16B

    // ---- prologue: stage entries 0,1,2 (global rows h0-1..h0+1), 9 DMAs ----
    stage_entry(vol, ring, 0, h0, om, o0, op);
    stage_entry(vol, ring, 1, h0, om, o0, op);
    stage_entry(vol, ring, 2, h0, om, o0, op);

    // register window: reg slot j%3 holds entry j's three plane-rows
    v4f wm[3], w0[3], wp[3];

    #pragma unroll
    for (int i = 0; i < HCW; ++i) {
        // distance-2 prefetch: entry i+3 into ring slot (i+3)&3 (overwrites
        // entry i-1, whose ds_reads retired at step i-1's lgkmcnt). Entries
        // run 0..17 (row h0+16 is the last halo row).
        if (i + 3 <= HCW + 1)
            stage_entry(vol, ring, i + 3, h0, om, o0, op);
        __builtin_amdgcn_sched_barrier(0);      // pin DMA issue above the wait

        // Per-wave VMEM FIFO at the wait (oldest->newest):
        //   [stage(i+2):3] [store(i-1):1] [stage(i+3):3]
        // vmcnt(4): entry i+2 resident; new DMAs + last store stay in flight.
        if (i == 0)            asm volatile("s_waitcnt vmcnt(3)" ::: "memory");
        else if (i + 3 <= HCW + 1) asm volatile("s_waitcnt vmcnt(4)" ::: "memory");
        else                   asm volatile("s_waitcnt vmcnt(1)" ::: "memory");
        __builtin_amdgcn_sched_barrier(0);      // no LDS-read hoist above wait

        // pull newly-resident entries into the register window
        if (i == 0) {
            #pragma unroll
            for (int j = 0; j < 3; ++j) {
                const float* e = cring + (j & 3) * EF;
                wm[j] = *(const v4f*)(e + 0 * W);
                w0[j] = *(const v4f*)(e + 1 * W);
                wp[j] = *(const v4f*)(e + 2 * W);
            }
        } else {
            const int j = i + 2, s = j % 3;
            const float* e = cring + (j & 3) * EF;
            wm[s] = *(const v4f*)(e + 0 * W);
            w0[s] = *(const v4f*)(e + 1 * W);
            wp[s] = *(const v4f*)(e + 2 * W);
        }

        const int a = i % 3, b = (i + 1) % 3, cc = (i + 2) % 3;

        // verified separable max (absmax 0.0 R6-R12)
        const v4f a3m = vmax4(vmax4(wm[a], wm[b]), wm[cc]);   // plane d-1, 3 rows
        const v4f a3p = vmax4(vmax4(wp[a], wp[b]), wp[cc]);   // plane d+1, 3 rows
        const v4f a20 = vmax4(w0[a], w0[cc]);                 // plane d, h +- 1
        const v4f v8  = vmax4(vmax4(a3m, a3p), a20);          // 8 non-center rows
        const v4f c   = w0[b];

        const float l8 = __shfl_up(v8.w, 1);     // lane0 garbage, masked
        const float r8 = __shfl_down(v8.x, 1);   // lane63 garbage, masked
        const float lc = __shfl_up(c.w, 1);
        const float rc = __shfl_down(c.x, 1);

        float n0 = fmaxf(fmaxf(l8,   v8.x), v8.y);
        float n1 = fmaxf(fmaxf(v8.x, v8.y), v8.z);
        float n2 = fmaxf(fmaxf(v8.y, v8.z), v8.w);
        float n3 = fmaxf(fmaxf(v8.z, v8.w), r8);
        n0 = fmaxf(n0, fmaxf(lc,  c.y));
        n1 = fmaxf(n1, fmaxf(c.x, c.z));
        n2 = fmaxf(n2, fmaxf(c.y, c.w));
        n3 = fmaxf(n3, fmaxf(c.z, rc));

        const int h = h0 + i;
        const bool hv = (h > 0) && (h < H - 1);   // wave-uniform
        const bool v  = hv && dv;
        v4f o;
        o.x = (v && lane > 0  && c.x > n0) ? c.x : 0.f;
        o.y = (v && c.y > n1) ? c.y : 0.f;
        o.z = (v && c.z > n2) ? c.z : 0.f;
        o.w = (v && lane < 63 && c.w > n3) ? c.w : 0.f;
        __builtin_nontemporal_store(o, (v4f*)(ovol + h * SH));   // nt: champion cfg
    }
}

extern "C" void kernel_launch(void* const* d_in, const int* in_sizes, int n_in,
                              void* d_out, int out_size, void* d_ws, size_t ws_size,
                              hipStream_t stream) {
    const float* x = (const float*)d_in[0];
    float* out = (float*)d_out;
    // blocks = BC * DG * HG = 16*8*16 = 2048, 256 threads, 3 blocks/CU
    nms3d_kernel<<<NWG, 256, 0, stream>>>(x, out);
}

// Round 8
// 223.314 us; speedup vs baseline: 1.0416x; 1.0377x over previous
//
#include <hip/hip_runtime.h>

// NMS3D (4,4,32,256,256) fp32, strict 26-neighbor max.
// R14: single-variable test on the R9 champion — nontemporal -> NORMAL stores.
// Everything else identical to R9 (36 KiB tile, 4 blocks/CU, 8192 independent
// blocks, stage -> one __syncthreads -> compute, no swizzle).
// Why: pipeline scorecard closed (R8 lockstep=85us, R12 reg-window=80us,
// R13 private ring=81us vs R9 simple=62us — R13 also exposed that vmcnt
// counts STORES, so per-step counted waits become store-latency-bound; R9's
// only wait precedes all stores). Remaining gap: 62us vs 35us HBM floor at
// ~3.6 TB/s effective, while the harness fill sustains 6.7 TB/s with NORMAL
// stores on the same machine. nt bypasses L2 -> no write-combining/reordering
// at the controllers, mixed with the cold read stream. R11's apparent
// refutation of normal stores was bundled with the XCD swizzle — unattributed.
// This round isolates the store mode.
// Math verified absmax 0.0 in R6-R13: separable vertical max + lane shuffles.

typedef float v4f __attribute__((ext_vector_type(4)));

constexpr int W  = 256;
constexpr int H  = 256;
constexpr int D  = 32;
constexpr int SH = W;
constexpr int SD = W * H;
constexpr int KD = 4;                  // d outputs per block (1 per wave)
constexpr int HC = 4;                  // h rows per block
constexpr int BC = 16;                 // B*CH
constexpr int DG = D / KD;             // 8
constexpr int HG = H / HC;             // 64
constexpr int NPL = KD + 2;            // 6 staged planes
constexpr int NR  = HC + 2;            // 6 staged rows per plane
constexpr int TROWS = NPL * NR;        // 36 rows of W floats = 36 KiB

__device__ __forceinline__ v4f vmax4(v4f a, v4f b) {
    return (v4f){fmaxf(a.x, b.x), fmaxf(a.y, b.y), fmaxf(a.z, b.z), fmaxf(a.w, b.w)};
}

__global__ __launch_bounds__(256, 4) void nms3d_kernel(const float* __restrict__ x,
                                                       float* __restrict__ out) {
    __shared__ float lds[TROWS * W];   // 36 KiB -> 4 blocks/CU

    const int blk  = blockIdx.x;
    const int wv   = threadIdx.x >> 6;   // 0..3
    const int lane = threadIdx.x & 63;
    const int hc   = blk & (HG - 1);            // fastest: h-neighbors share halo in L2
    const int dg   = (blk >> 6) & (DG - 1);
    const int bc   = blk >> 9;
    const int d0   = dg * KD;
    const int h0   = hc * HC;

    const float* vol = x + bc * (D * SD);

    // ---- stage 36 rows; wave wv stages flat rows t = wv*9 .. wv*9+8 ----
    #pragma unroll
    for (int u = 0; u < TROWS / 4; ++u) {       // 9 DMA instrs per wave
        const int t = wv * (TROWS / 4) + u;
        const int j = t / NR;
        const int r = t - j * NR;
        int p = d0 - 1 + j;  p = p < 0 ? 0 : (p > D - 1 ? D - 1 : p);
        int hh = h0 - 1 + r; hh = hh < 0 ? 0 : (hh > H - 1 ? H - 1 : hh);
        const float* gp = vol + p * SD + hh * SH + (lane << 2);
        // lane i's 16B land at ldsbase + 16*i -> exactly row-major row layout
        __builtin_amdgcn_global_load_lds(
            (const __attribute__((address_space(1))) unsigned int*)gp,
            (__attribute__((address_space(3))) unsigned int*)&lds[(j * NR + r) * W],
            16, 0, 0);
    }
    __syncthreads();   // drains vmcnt (DMA) then barrier — the block's only sync,
                       // and it happens BEFORE any store exists (R13 lesson).

    // ---- compute: wave wv handles output plane d = d0 + wv ----
    const int d = d0 + wv;
    const bool dv = (d > 0) && (d < D - 1);
    float* ovol = out + bc * (D * SD) + d * SD + (lane << 2);

    const float* Lm = lds + (wv * NR) * W + (lane << 2);        // plane d-1
    const float* L0 = lds + ((wv + 1) * NR) * W + (lane << 2);  // plane d
    const float* Lp = lds + ((wv + 2) * NR) * W + (lane << 2);  // plane d+1

    // rolling 3-row window per plane, slot = (row mod 3), fully unrolled
    v4f rm[3], r0[3], rp[3];
    rm[0] = *(const v4f*)(Lm + 0 * W); r0[0] = *(const v4f*)(L0 + 0 * W); rp[0] = *(const v4f*)(Lp + 0 * W);
    rm[1] = *(const v4f*)(Lm + 1 * W); r0[1] = *(const v4f*)(L0 + 1 * W); rp[1] = *(const v4f*)(Lp + 1 * W);

    #pragma unroll
    for (int i = 0; i < HC; ++i) {
        const int s0 = i % 3, s1 = (i + 1) % 3, s2 = (i + 2) % 3;
        rm[s2] = *(const v4f*)(Lm + (i + 2) * W);
        r0[s2] = *(const v4f*)(L0 + (i + 2) * W);
        rp[s2] = *(const v4f*)(Lp + (i + 2) * W);

        // separable: per-plane maxes over the 3 h-rows
        const v4f a3m = vmax4(vmax4(rm[s0], rm[s1]), rm[s2]);   // plane d-1, all rows
        const v4f a3p = vmax4(vmax4(rp[s0], rp[s1]), rp[s2]);   // plane d+1, all rows
        const v4f a20 = vmax4(r0[s0], r0[s2]);                  // plane d, h +- 1
        const v4f v8  = vmax4(vmax4(a3m, a3p), a20);            // 8 non-center rows
        const v4f c   = r0[s1];

        const float l8 = __shfl_up(v8.w, 1);     // lane0 garbage, masked
        const float r8 = __shfl_down(v8.x, 1);   // lane63 garbage, masked
        const float lc = __shfl_up(c.w, 1);
        const float rc = __shfl_down(c.x, 1);

        float n0 = fmaxf(fmaxf(l8,   v8.x), v8.y);
        float n1 = fmaxf(fmaxf(v8.x, v8.y), v8.z);
        float n2 = fmaxf(fmaxf(v8.y, v8.z), v8.w);
        float n3 = fmaxf(fmaxf(v8.z, v8.w), r8);
        n0 = fmaxf(n0, fmaxf(lc,  c.y));
        n1 = fmaxf(n1, fmaxf(c.x, c.z));
        n2 = fmaxf(n2, fmaxf(c.y, c.w));
        n3 = fmaxf(n3, fmaxf(c.z, rc));

        const int h = h0 + i;
        const bool hv = (h > 0) && (h < H - 1);   // wave-uniform
        const bool v  = hv && dv;
        v4f o;
        o.x = (v && lane > 0  && c.x > n0) ? c.x : 0.f;
        o.y = (v && c.y > n1) ? c.y : 0.f;
        o.z = (v && c.z > n2) ? c.z : 0.f;
        o.w = (v && lane < 63 && c.w > n3) ? c.w : 0.f;
        // R14 single change: NORMAL store (write-back via L2). The fill
        // kernel sustains 6.7 TB/s with this path; nt measured ~3.6 eff.
        *(v4f*)(ovol + h * SH) = o;
    }
}

extern "C" void kernel_launch(void* const* d_in, const int* in_sizes, int n_in,
                              void* d_out, int out_size, void* d_ws, size_t ws_size,
                              hipStream_t stream) {
    const float* x = (const float*)d_in[0];
    float* out = (float*)d_out;
    // blocks = BC * DG * HG = 16*8*64 = 8192, 256 threads each, 4 blocks/CU
    const int grid = BC * DG * HG;
    nms3d_kernel<<<grid, 256, 0, stream>>>(x, out);
}